// Round 1
// baseline (105.995 us; speedup 1.0000x reference)
//
#include <hip/hip_runtime.h>

#define Bb 4
#define Nn 1024
#define Dd 128
#define Hh 64
#define NT 32            // tiles per dim (N/32)
#define NPAIRS 528       // NT*(NT+1)/2

__device__ __forceinline__ float fast_tanh(float x) {
    const float e = __expf(2.0f * x);
    return __fdividef(e - 1.0f, e + 1.0f);
}

// word-index swizzle: spread row's columns across bank groups
__device__ __forceinline__ int swz_idx(int row, int cw) {
    return row * Hh + (cw ^ (((row >> 2) & 7) << 2));
}

// ---------------- Kernel A: projection ----------------
// HI2[row][h] = sum_d emb[row][d]*W1[d][h] + b1[h]
// HJ [row][h] = sum_d emb[row][d]*W1[128+d][h]
// 256 blocks x 256 threads; 16 rows/block; thread: r=tid>>4, h4=(tid&15)*4
__global__ __launch_bounds__(256) void proj_kernel(
    const float* __restrict__ emb, const float* __restrict__ W1,
    const float* __restrict__ b1, float* __restrict__ HI2, float* __restrict__ HJ)
{
    __shared__ float se[16][132];   // pad 132: r*132 % 32 distinct per r
    const int tid = threadIdx.x;
    const int row0 = blockIdx.x * 16;
    // stage 16 rows of emb (2048 floats = 512 float4)
    for (int l = tid; l < 512; l += 256) {
        const int r = l >> 5;       // 32 float4 per row
        const int c = l & 31;
        const float4 v = *(const float4*)(emb + (size_t)(row0 + r) * Dd + c * 4);
        *(float4*)&se[r][c * 4] = v;
    }
    __syncthreads();
    const int r  = tid >> 4;
    const int h4 = (tid & 15) * 4;
    float4 acc1 = *(const float4*)(b1 + h4);
    float4 acc2 = make_float4(0.f, 0.f, 0.f, 0.f);
    const float* er = se[r];
    #pragma unroll 4
    for (int d = 0; d < Dd; ++d) {
        const float ev = er[d];
        const float4 wa = *(const float4*)(W1 + (size_t)d * Hh + h4);
        const float4 wb = *(const float4*)(W1 + (size_t)(d + Dd) * Hh + h4);
        acc1.x = fmaf(ev, wa.x, acc1.x); acc1.y = fmaf(ev, wa.y, acc1.y);
        acc1.z = fmaf(ev, wa.z, acc1.z); acc1.w = fmaf(ev, wa.w, acc1.w);
        acc2.x = fmaf(ev, wb.x, acc2.x); acc2.y = fmaf(ev, wb.y, acc2.y);
        acc2.z = fmaf(ev, wb.z, acc2.z); acc2.w = fmaf(ev, wb.w, acc2.w);
    }
    *(float4*)(HI2 + (size_t)(row0 + r) * Hh + h4) = acc1;
    *(float4*)(HJ  + (size_t)(row0 + r) * Hh + h4) = acc2;
}

// ---------------- Kernel B: pair scoring ----------------
// grid = Bb * NPAIRS blocks; block = 256 threads (16x16), 2x2 micro-tile,
// 32x32 output tile; computes out[i][j] = out[j][i] = -0.5*(tanh(s_ij+b2)+tanh(s_ji+b2))
__global__ __launch_bounds__(256, 4) void score_kernel(
    const float* __restrict__ HI2, const float* __restrict__ HJ,
    const float* __restrict__ W2, const float* __restrict__ b2p,
    float* __restrict__ out)
{
    __shared__ float sAi[32 * Hh];  // HI2 rows of i-range
    __shared__ float sBi[32 * Hh];  // HJ  rows of i-range
    __shared__ float sAj[32 * Hh];  // HI2 rows of j-range
    __shared__ float sBj[32 * Hh];  // HJ  rows of j-range
    __shared__ float sW[Hh];

    const int tid = threadIdx.x;
    const int blk = blockIdx.x;
    const int b = blk / NPAIRS;
    const int p = blk - b * NPAIRS;
    // triangular decode: (ti <= tj)
    int ti = 0, accum = 0;
    while (accum + (NT - ti) <= p) { accum += NT - ti; ++ti; }
    const int tj = ti + (p - accum);
    const int ri0 = ti * 32, rj0 = tj * 32;

    const float* HIb = HI2 + (size_t)b * Nn * Hh;
    const float* HJb = HJ  + (size_t)b * Nn * Hh;

    if (tid < Hh) sW[tid] = W2[tid];
    // stage 4 panels (each 32 rows x 64 f32), XOR-swizzled columns
    for (int l = tid; l < 2048; l += 256) {
        const int which = l >> 9;
        const int rem   = l & 511;
        const int row   = rem >> 4;
        const int cw    = (rem & 15) * 4;
        const float* src;
        float* dst;
        if (which == 0)      { src = HIb + (size_t)(ri0 + row) * Hh; dst = sAi; }
        else if (which == 1) { src = HJb + (size_t)(ri0 + row) * Hh; dst = sBi; }
        else if (which == 2) { src = HIb + (size_t)(rj0 + row) * Hh; dst = sAj; }
        else                 { src = HJb + (size_t)(rj0 + row) * Hh; dst = sBj; }
        const float4 v = *(const float4*)(src + cw);
        *(float4*)&dst[swz_idx(row, cw)] = v;
    }
    __syncthreads();

    const int tx = tid & 15;   // j direction
    const int ty = tid >> 4;   // i direction

    float s_ij[2][2] = {{0.f, 0.f}, {0.f, 0.f}};
    float s_ji[2][2] = {{0.f, 0.f}, {0.f, 0.f}};

    for (int hc = 0; hc < 16; ++hc) {
        const int cw = hc * 4;
        const float4 w = *(const float4*)(sW + cw);
        float4 ai[2], bi[2], aj[2], bj[2];
        #pragma unroll
        for (int r = 0; r < 2; ++r) {
            ai[r] = *(const float4*)&sAi[swz_idx(ty * 2 + r, cw)];
            bi[r] = *(const float4*)&sBi[swz_idx(ty * 2 + r, cw)];
        }
        #pragma unroll
        for (int c = 0; c < 2; ++c) {
            aj[c] = *(const float4*)&sAj[swz_idx(tx * 2 + c, cw)];
            bj[c] = *(const float4*)&sBj[swz_idx(tx * 2 + c, cw)];
        }
        #pragma unroll
        for (int r = 0; r < 2; ++r) {
            #pragma unroll
            for (int c = 0; c < 2; ++c) {
                float t;
                t = fmaxf(ai[r].x + bj[c].x, 0.f); s_ij[r][c] = fmaf(t, w.x, s_ij[r][c]);
                t = fmaxf(ai[r].y + bj[c].y, 0.f); s_ij[r][c] = fmaf(t, w.y, s_ij[r][c]);
                t = fmaxf(ai[r].z + bj[c].z, 0.f); s_ij[r][c] = fmaf(t, w.z, s_ij[r][c]);
                t = fmaxf(ai[r].w + bj[c].w, 0.f); s_ij[r][c] = fmaf(t, w.w, s_ij[r][c]);
                t = fmaxf(aj[c].x + bi[r].x, 0.f); s_ji[r][c] = fmaf(t, w.x, s_ji[r][c]);
                t = fmaxf(aj[c].y + bi[r].y, 0.f); s_ji[r][c] = fmaf(t, w.y, s_ji[r][c]);
                t = fmaxf(aj[c].z + bi[r].z, 0.f); s_ji[r][c] = fmaf(t, w.z, s_ji[r][c]);
                t = fmaxf(aj[c].w + bi[r].w, 0.f); s_ji[r][c] = fmaf(t, w.w, s_ji[r][c]);
            }
        }
    }

    const float bb = b2p[0];
    float vals[2][2];
    #pragma unroll
    for (int r = 0; r < 2; ++r)
        #pragma unroll
        for (int c = 0; c < 2; ++c)
            vals[r][c] = -0.5f * (fast_tanh(s_ij[r][c] + bb) + fast_tanh(s_ji[r][c] + bb));

    float* outb = out + (size_t)b * Nn * Nn;
    const int i0 = ri0 + ty * 2;
    const int j0 = rj0 + tx * 2;
    // direct tile
    #pragma unroll
    for (int r = 0; r < 2; ++r)
        *(float2*)(outb + (size_t)(i0 + r) * Nn + j0) = make_float2(vals[r][0], vals[r][1]);
    // mirrored tile (same values — output is symmetric)
    #pragma unroll
    for (int c = 0; c < 2; ++c)
        *(float2*)(outb + (size_t)(j0 + c) * Nn + i0) = make_float2(vals[0][c], vals[1][c]);
}

extern "C" void kernel_launch(void* const* d_in, const int* in_sizes, int n_in,
                              void* d_out, int out_size, void* d_ws, size_t ws_size,
                              hipStream_t stream) {
    const float* emb = (const float*)d_in[0];
    const float* W1  = (const float*)d_in[1];
    const float* b1  = (const float*)d_in[2];
    const float* W2  = (const float*)d_in[3];
    const float* b2  = (const float*)d_in[4];
    float* out = (float*)d_out;
    float* HI2 = (float*)d_ws;                       // 4096*64 f32 = 1 MB
    float* HJ  = HI2 + (size_t)Bb * Nn * Hh;         // 1 MB

    proj_kernel<<<(Bb * Nn) / 16, 256, 0, stream>>>(emb, W1, b1, HI2, HJ);
    score_kernel<<<Bb * NPAIRS, 256, 0, stream>>>(HI2, HJ, W2, b2, out);
}